// Round 1
// baseline (261.908 us; speedup 1.0000x reference)
//
#include <hip/hip_runtime.h>
#include <hip/hip_fp16.h>
#include <math.h>

#define D 128
#define GM 64            // rows per GEMM tile in prep2
#define CONV_BLOCKS 2048
#define CONV_BLOCKS_OLD 1024

typedef _Float16 f16x8 __attribute__((ext_vector_type(8)));
typedef float    f32x4 __attribute__((ext_vector_type(4)));
typedef _Float16 h2_t  __attribute__((ext_vector_type(2)));

__device__ __forceinline__ float dot2acc(unsigned ua, unsigned ub, float c) {
#if __has_builtin(__builtin_amdgcn_fdot2)
  return __builtin_amdgcn_fdot2(__builtin_bit_cast(h2_t, ua),
                                __builtin_bit_cast(h2_t, ub), c, false);
#else
  __half2 a = __builtin_bit_cast(__half2, ua);
  __half2 b = __builtin_bit_cast(__half2, ub);
  float2 fa = __half22float2(a), fb = __half22float2(b);
  return fmaf(fa.x, fb.x, fmaf(fa.y, fb.y, c));
#endif
}

__device__ __forceinline__ unsigned pack2(float x, float y) {
  __half2 h;
  h.x = __float2half_rn(x);
  h.y = __float2half_rn(y);
  return __builtin_bit_cast(unsigned, h);
}

// ---------------- K1: W [k][n] fp32 -> WhT [n][k] fp16 (32 KB, L1-resident) ----
__global__ __launch_bounds__(256) void wt_kernel(const float* __restrict__ W,
                                                 __half* __restrict__ WhT) {
  const int n  = blockIdx.x * 16 + (threadIdx.x >> 4);   // 8 blocks -> n in [0,128)
  const int k0 = (threadIdx.x & 15) * 8;
  float w[8];
  #pragma unroll
  for (int kk = 0; kk < 8; kk++) w[kk] = W[(k0 + kk) * D + n];
  uint4 u;
  u.x = pack2(w[0], w[1]); u.y = pack2(w[2], w[3]);
  u.z = pack2(w[4], w[5]); u.w = pack2(w[6], w[7]);
  *(uint4*)(WhT + n * D + k0) = u;
}

// ---------------- K2: fused GEMM (Y = Xout @ W, fp16 out) + Xin fp32->fp16 ----
// GEMM blocks: 64-row tile, 16 KB LDS only (fp16 A, XOR-swizzled; reused as sC).
// B fragments read directly from L1-resident WhT. Convert blocks: grid-stride.
__global__ __launch_bounds__(256) void prep2_kernel(
    const float* __restrict__ Xout, const float* __restrict__ Xin,
    const __half* __restrict__ WhT, __half* __restrict__ Yh,
    __half* __restrict__ Xh, int N, int gemm_blocks)
{
  __shared__ __align__(16) __half sA[GM * D];   // 16 KB; reused as sC in epilogue

  const int tid = threadIdx.x;

  if ((int)blockIdx.x >= gemm_blocks) {
    // ---- convert role: Xh = (half)Xin ----
    const int cb = blockIdx.x - gemm_blocks;
    const int n4 = N * (D / 4);
    const int stride = CONV_BLOCKS * 256 * 4;
    for (int base = (cb * 256 + tid) * 4; base < n4; base += stride) {
      float4 v[4];
      #pragma unroll
      for (int j = 0; j < 4; j++)
        if (base + j < n4) v[j] = ((const float4*)Xin)[base + j];
      #pragma unroll
      for (int j = 0; j < 4; j++)
        if (base + j < n4) {
          uint2 u;
          u.x = pack2(v[j].x, v[j].y);
          u.y = pack2(v[j].z, v[j].w);
          ((uint2*)Xh)[base + j] = u;
        }
    }
    return;
  }

  // ---- GEMM role ----
  const int row0 = blockIdx.x * GM;

  // Stage A: 1024 granules (16B fp16 each = 32B fp32 src); 4 granules/thread.
  // All 8 float4 loads issued first (deep MLP), then convert + swizzled LDS write.
  float4 v[8];
  #pragma unroll
  for (int i = 0; i < 4; i++) {
    int gi = tid + i * 256;            // granule id 0..1023
    int r = gi >> 4, q = gi & 15;
    int gr = row0 + r;
    if (gr < N) {
      const float4* s = (const float4*)(Xout + (size_t)gr * D + q * 8);
      v[2*i]   = s[0];
      v[2*i+1] = s[1];
    } else {
      v[2*i]   = make_float4(0.f, 0.f, 0.f, 0.f);
      v[2*i+1] = make_float4(0.f, 0.f, 0.f, 0.f);
    }
  }
  #pragma unroll
  for (int i = 0; i < 4; i++) {
    int gi = tid + i * 256;
    int r = gi >> 4, q = gi & 15;
    uint4 u;
    u.x = pack2(v[2*i].x,   v[2*i].y);
    u.y = pack2(v[2*i].z,   v[2*i].w);
    u.z = pack2(v[2*i+1].x, v[2*i+1].y);
    u.w = pack2(v[2*i+1].z, v[2*i+1].w);
    // swizzle: granule q -> q ^ (r&7); keeps afrag ds_read_b128 2-way (free)
    *(uint4*)(sA + r * D + ((q ^ (r & 7)) << 3)) = u;
  }
  __syncthreads();

  const int lane = tid & 63, wave = tid >> 6;
  const int m = lane & 15, quad = lane >> 4;
  const int rloc = wave * 16 + m;

  f32x4 acc[8];
  #pragma unroll
  for (int ct = 0; ct < 8; ct++) acc[ct] = (f32x4){0.f, 0.f, 0.f, 0.f};

  #pragma unroll
  for (int ks = 0; ks < 4; ks++) {
    const int g = ks * 4 + quad;       // k-granule: k = g*8 + j
    f16x8 bfrag[8];
    #pragma unroll
    for (int ct = 0; ct < 8; ct++)
      bfrag[ct] = *(const f16x8*)(WhT + (size_t)(ct * 16 + m) * D + g * 8);
    f16x8 afrag = *(const f16x8*)(sA + rloc * D + ((g ^ (rloc & 7)) << 3));
    #pragma unroll
    for (int ct = 0; ct < 8; ct++)
      acc[ct] = __builtin_amdgcn_mfma_f32_16x16x32_f16(
          afrag, bfrag[ct], acc[ct], 0, 0, 0);
  }

  // Epilogue: acc -> sC (reuse sA) -> coalesced uint4 global stores.
  __syncthreads();
  __half* sC = sA;
  #pragma unroll
  for (int ct = 0; ct < 8; ct++)
    #pragma unroll
    for (int reg = 0; reg < 4; reg++) {
      int r = wave * 16 + quad * 4 + reg;
      sC[r * D + ct * 16 + m] = __float2half_rn(acc[ct][reg]);
    }
  __syncthreads();
  #pragma unroll
  for (int i = 0; i < 4; i++) {
    int gi = tid + i * 256;            // 0..1023 granules
    int r = gi >> 4, q = gi & 15;
    int gr = row0 + r;
    if (gr < N)
      *(uint4*)(Yh + (size_t)gr * D + q * 8) = *(const uint4*)(sC + r * D + q * 8);
  }
}

// ---------------- Old fused prep (kept as fallback if ws has no room for WhT) --
__global__ __launch_bounds__(256) void prep_kernel(
    const float* __restrict__ Xout, const float* __restrict__ Xin,
    const float* __restrict__ W, __half* __restrict__ Yh,
    __half* __restrict__ Xh, int N, int gemm_blocks)
{
  __shared__ __align__(16) __half sA[128 * 128];
  __shared__ __align__(16) __half sB[128 * 128];

  const int tid = threadIdx.x;

  if ((int)blockIdx.x >= gemm_blocks) {
    const int cb = blockIdx.x - gemm_blocks;
    const int n4 = N * (D / 4);
    const int stride = CONV_BLOCKS_OLD * 256 * 4;
    for (int base = (cb * 256 + tid) * 4; base < n4; base += stride) {
      float4 v[4];
      #pragma unroll
      for (int j = 0; j < 4; j++)
        if (base + j < n4) v[j] = ((const float4*)Xin)[base + j];
      #pragma unroll
      for (int j = 0; j < 4; j++)
        if (base + j < n4) {
          uint2 u;
          u.x = pack2(v[j].x, v[j].y);
          u.y = pack2(v[j].z, v[j].w);
          ((uint2*)Xh)[base + j] = u;
        }
    }
    return;
  }

  const int row0 = blockIdx.x * 128;

  #pragma unroll
  for (int i = 0; i < 16; i++) {
    int idx = tid + i * 256;
    int q   = idx & 31;
    int r   = idx >> 5;
    int gr  = row0 + r;
    float4 v = make_float4(0.f, 0.f, 0.f, 0.f);
    if (gr < N) v = *(const float4*)(Xout + (size_t)gr * D + q * 4);
    uint2 u;
    u.x = pack2(v.x, v.y);
    u.y = pack2(v.z, v.w);
    int g   = q >> 1;
    int sub = q & 1;
    int off = r * 128 + (((g + r) & 15) << 3) + (sub << 2);
    *(uint2*)(sA + off) = u;
  }
  #pragma unroll
  for (int i = 0; i < 64; i++) {
    int o = tid + i * 256;
    int k = o >> 7;
    int n = o & 127;
    __half h = __float2half_rn(W[o]);
    int gk = k >> 3;
    sB[n * 128 + (((gk + n) & 15) << 3) + (k & 7)] = h;
  }
  __syncthreads();

  const int wave = tid >> 6;
  const int lane = tid & 63;
  const int m    = lane & 15;
  const int quad = lane >> 4;

  f32x4 acc[2][8];
  #pragma unroll
  for (int rt = 0; rt < 2; rt++)
    #pragma unroll
    for (int ct = 0; ct < 8; ct++)
      acc[rt][ct] = (f32x4){0.f, 0.f, 0.f, 0.f};

  #pragma unroll
  for (int ks = 0; ks < 4; ks++) {
    const int g = ks * 4 + quad;
    f16x8 bfrag[8];
    #pragma unroll
    for (int ct = 0; ct < 8; ct++) {
      int n = ct * 16 + m;
      bfrag[ct] = *(const f16x8*)(sB + n * 128 + (((g + n) & 15) << 3));
    }
    #pragma unroll
    for (int rt = 0; rt < 2; rt++) {
      int r = wave * 32 + rt * 16 + m;
      f16x8 afrag = *(const f16x8*)(sA + r * 128 + (((g + r) & 15) << 3));
      #pragma unroll
      for (int ct = 0; ct < 8; ct++)
        acc[rt][ct] = __builtin_amdgcn_mfma_f32_16x16x32_f16(
            afrag, bfrag[ct], acc[rt][ct], 0, 0, 0);
    }
  }

  __syncthreads();
  __half* sC = sA;
  #pragma unroll
  for (int rt = 0; rt < 2; rt++)
    #pragma unroll
    for (int reg = 0; reg < 4; reg++) {
      int r = wave * 32 + rt * 16 + quad * 4 + reg;
      #pragma unroll
      for (int ct = 0; ct < 8; ct++)
        sC[r * 128 + ct * 16 + m] = __float2half_rn(acc[rt][ct][reg]);
    }
  __syncthreads();
  #pragma unroll
  for (int i = 0; i < 8; i++) {
    int idx = tid + i * 256;
    int r   = idx >> 4;
    int gq  = idx & 15;
    int gr  = row0 + r;
    if (gr < N)
      *(uint4*)(Yh + (size_t)gr * D + gq * 8) = *(const uint4*)(sC + r * 128 + gq * 8);
  }
}

// ---------------- K3: out[e] = sigmoid(Yh[src] . Xh[dst]), 4 edges / 16 lanes --
__global__ __launch_bounds__(256) void edge_dot4_kernel(
    const __half* __restrict__ Yh, const __half* __restrict__ Xh,
    const int* __restrict__ idx, float* __restrict__ out, int E)
{
  long long gid = (long long)blockIdx.x * 256 + threadIdx.x;
  int slot = (int)(gid >> 4);
  int l    = (int)(gid & 15);
  int e0 = slot * 4;
  if (e0 >= E) return;

  int s[4], d[4];
  #pragma unroll
  for (int i = 0; i < 4; i++) {
    int e = e0 + i; if (e > E - 1) e = E - 1;
    s[i] = idx[e];
    d[i] = idx[E + e];
  }
  uint4 a[4], b[4];
  #pragma unroll
  for (int i = 0; i < 4; i++) a[i] = ((const uint4*)(Yh + (size_t)s[i] * D))[l];
  #pragma unroll
  for (int i = 0; i < 4; i++) b[i] = ((const uint4*)(Xh + (size_t)d[i] * D))[l];

  float p[4];
  #pragma unroll
  for (int i = 0; i < 4; i++) {
    float t = 0.f;
    t = dot2acc(a[i].x, b[i].x, t);
    t = dot2acc(a[i].y, b[i].y, t);
    t = dot2acc(a[i].z, b[i].z, t);
    t = dot2acc(a[i].w, b[i].w, t);
    p[i] = t;
  }
  #pragma unroll
  for (int i = 0; i < 4; i++) {
    p[i] += __shfl_xor(p[i], 8);
    p[i] += __shfl_xor(p[i], 4);
    p[i] += __shfl_xor(p[i], 2);
    p[i] += __shfl_xor(p[i], 1);
  }

  if (l == 0) {
    float4 o;
    o.x = 1.0f / (1.0f + __expf(-p[0]));
    o.y = 1.0f / (1.0f + __expf(-p[1]));
    o.z = 1.0f / (1.0f + __expf(-p[2]));
    o.w = 1.0f / (1.0f + __expf(-p[3]));
    if (e0 + 3 < E) {
      *(float4*)(out + e0) = o;
    } else {
      out[e0] = o.x;
      if (e0 + 1 < E) out[e0 + 1] = o.y;
      if (e0 + 2 < E) out[e0 + 2] = o.z;
    }
  }
}

// ---------------- Fallback: direct bilinear per edge (only if ws too small) ----
__global__ __launch_bounds__(256) void edge_bilinear_direct_kernel(
    const float* __restrict__ Xout, const float* __restrict__ Xin,
    const float* __restrict__ W, const int* __restrict__ idx,
    float* __restrict__ out, int E)
{
  long long gid = (long long)blockIdx.x * 256 + threadIdx.x;
  int e = (int)(gid >> 6);
  if (e >= E) return;
  int l = (int)(gid & 63);

  int src = idx[e];
  int dst = idx[E + e];
  const float* a = Xout + (size_t)src * D;
  const float* b = Xin  + (size_t)dst * D;

  float s = 0.f;
  #pragma unroll
  for (int kk = 0; kk < 2; kk++) {
    int k = l + kk * 64;
    float ak = a[k];
    float t = 0.f;
    #pragma unroll 8
    for (int j = 0; j < D; j++) t = fmaf(W[(size_t)k * D + j], b[j], t);
    s = fmaf(ak, t, s);
  }
  #pragma unroll
  for (int off = 32; off >= 1; off >>= 1) s += __shfl_xor(s, off);
  if (l == 0) out[e] = 1.0f / (1.0f + __expf(-s));
}

extern "C" void kernel_launch(void* const* d_in, const int* in_sizes, int n_in,
                              void* d_out, int out_size, void* d_ws, size_t ws_size,
                              hipStream_t stream) {
  const float* x_in  = (const float*)d_in[0];   // [N, 128]
  const float* x_out = (const float*)d_in[1];   // [N, 128]
  const int*   eidx  = (const int*)d_in[2];     // [2, E]
  const float* W     = (const float*)d_in[3];   // [128,128]
  float* out = (float*)d_out;

  const int N = in_sizes[0] / D;
  const int E = in_sizes[2] / 2;

  const size_t half_rows = (size_t)N * D * sizeof(__half);  // 25.6 MB each
  const size_t wht_bytes = (size_t)D * D * sizeof(__half);  // 32 KB

  if (ws_size >= 2 * half_rows + wht_bytes) {
    __half* Yh  = (__half*)d_ws;
    __half* Xh  = (__half*)((char*)d_ws + half_rows);
    __half* WhT = (__half*)((char*)d_ws + 2 * half_rows);

    wt_kernel<<<dim3(8), 256, 0, stream>>>(W, WhT);

    int gemm_blocks = (N + GM - 1) / GM;
    dim3 g1(gemm_blocks + CONV_BLOCKS);
    prep2_kernel<<<g1, 256, 0, stream>>>(x_out, x_in, WhT, Yh, Xh, N, gemm_blocks);

    long long slots = ((long long)E + 3) / 4;
    long long total = slots * 16;
    dim3 g2((unsigned)((total + 255) / 256));
    edge_dot4_kernel<<<g2, 256, 0, stream>>>(Yh, Xh, eidx, out, E);
  } else if (ws_size >= 2 * half_rows) {
    __half* Yh = (__half*)d_ws;
    __half* Xh = (__half*)((char*)d_ws + half_rows);

    int gemm_blocks = (N + 127) / 128;
    dim3 g1(gemm_blocks + CONV_BLOCKS_OLD);
    prep_kernel<<<g1, 256, 0, stream>>>(x_out, x_in, W, Yh, Xh, N, gemm_blocks);

    long long slots = ((long long)E + 3) / 4;
    long long total = slots * 16;
    dim3 g2((unsigned)((total + 255) / 256));
    edge_dot4_kernel<<<g2, 256, 0, stream>>>(Yh, Xh, eidx, out, E);
  } else {
    long long total = (long long)E * 64;
    dim3 g((unsigned)((total + 255) / 256));
    edge_bilinear_direct_kernel<<<g, 256, 0, stream>>>(x_out, x_in, W, eidx, out, E);
  }
}